// Round 1
// baseline (2235.043 us; speedup 1.0000x reference)
//
#include <hip/hip_runtime.h>
#include <hip/hip_bf16.h>

// GCN 2-layer forward, fp32 throughout.
// Pipeline: deg -> dinv ; h1 = x@W1 ; agg1 = selfloop + scatter ;
//           h2 = relu(agg1+b1)@W2 ; agg2(out) = selfloop + scatter ; log_softmax.

__device__ __forceinline__ void atomAddF(float* p, float v) {
    unsafeAtomicAdd(p, v);   // hw global_atomic_add_f32 on gfx950
}

__global__ __launch_bounds__(256) void k_init_deg(float* __restrict__ deg, int N) {
    int i = blockIdx.x * 256 + threadIdx.x;
    if (i < N) deg[i] = 1.0f;   // self-loop
}

__global__ __launch_bounds__(256) void k_accum_deg(const int* __restrict__ dst,
                                                   float* __restrict__ deg, int E) {
    int e = blockIdx.x * 256 + threadIdx.x;
    if (e < E) atomAddF(&deg[dst[e]], 1.0f);
}

__global__ __launch_bounds__(256) void k_make_dinv(float* __restrict__ deg, int N) {
    int i = blockIdx.x * 256 + threadIdx.x;
    if (i < N) deg[i] = rsqrtf(deg[i]);   // in-place: deg -> dinv
}

// out[r][c] = sum_k f(A[r][k]) * W[k][c];  f = relu(x + bin[k]) if TRANS_IN.
// 256 threads: thread = (rl rows) x (C4 col-quads). W + bias + x-tile in LDS.
template<int IN_C, int OUT_C, bool TRANS_IN>
__global__ __launch_bounds__(256) void k_mm(const float* __restrict__ A,
                                            const float* __restrict__ W,
                                            const float* __restrict__ bin,
                                            float* __restrict__ out, int n_rows) {
    constexpr int C4   = OUT_C / 4;     // threads per row
    constexpr int ROWS = 256 / C4;      // rows per tile (16 for 64-out, 32 for 32-out)
    __shared__ float Ws[IN_C][OUT_C];
    __shared__ float xs[ROWS][IN_C + 1];   // +1 pad: rl-groups land in distinct banks
    __shared__ float bs[IN_C];

    const int tid = threadIdx.x;
    for (int i = tid; i < IN_C * OUT_C; i += 256)
        Ws[i / OUT_C][i % OUT_C] = W[i];
    if (tid < IN_C) bs[tid] = TRANS_IN ? bin[tid] : 0.0f;

    const int c4 = (tid % C4) * 4;
    const int rl = tid / C4;
    const int tiles = (n_rows + ROWS - 1) / ROWS;

    for (int t = blockIdx.x; t < tiles; t += gridDim.x) {
        const int r0 = t * ROWS;
        __syncthreads();                         // xs safe to overwrite
        for (int i = tid; i < ROWS * IN_C; i += 256) {
            int r = i / IN_C, k = i % IN_C;
            float v = 0.0f;
            if (r0 + r < n_rows) {
                v = A[(long)(r0 + r) * IN_C + k];
                if (TRANS_IN) v = fmaxf(v + bs[k], 0.0f);
            }
            xs[r][k] = v;
        }
        __syncthreads();

        float4 acc = {0.f, 0.f, 0.f, 0.f};
        #pragma unroll
        for (int k = 0; k < IN_C; ++k) {
            const float a = xs[rl][k];
            const float4 w4 = *reinterpret_cast<const float4*>(&Ws[k][c4]);
            acc.x += a * w4.x; acc.y += a * w4.y;
            acc.z += a * w4.z; acc.w += a * w4.w;
        }
        const int row = r0 + rl;
        if (row < n_rows)
            *reinterpret_cast<float4*>(&out[(long)row * OUT_C + c4]) = acc;
    }
}

// agg[i][:] = h[i][:] * dinv[i]^2   (self-loop term; also zero-inits poisoned agg)
template<int F>
__global__ __launch_bounds__(256) void k_selfinit(const float* __restrict__ h,
                                                  const float* __restrict__ dinv,
                                                  float* __restrict__ agg, long total4) {
    long i = (long)blockIdx.x * 256 + threadIdx.x;   // index over float4s
    if (i >= total4) return;
    const int n = (int)(i / (F / 4));
    const float di = dinv[n];
    const float w = di * di;
    float4 v = *reinterpret_cast<const float4*>(&h[i * 4]);
    v.x *= w; v.y *= w; v.z *= w; v.w *= w;
    *reinterpret_cast<float4*>(&agg[i * 4]) = v;
}

// agg[dst] += h[src] * dinv[src]*dinv[dst];  F/4 lanes per edge, float4 gather.
template<int F>
__global__ __launch_bounds__(256) void k_scatter(const int* __restrict__ src,
                                                 const int* __restrict__ dst,
                                                 const float* __restrict__ dinv,
                                                 const float* __restrict__ h,
                                                 float* __restrict__ agg, int E) {
    constexpr int LPE = F / 4;
    const long tid = (long)blockIdx.x * 256 + threadIdx.x;
    const int e = (int)(tid / LPE);
    if (e >= E) return;
    const int q = (int)(tid % LPE) * 4;
    const int s = src[e], d = dst[e];
    const float w = dinv[s] * dinv[d];
    const float4 v = *reinterpret_cast<const float4*>(&h[(long)s * F + q]);
    float* ap = &agg[(long)d * F + q];
    atomAddF(ap + 0, v.x * w);
    atomAddF(ap + 1, v.y * w);
    atomAddF(ap + 2, v.z * w);
    atomAddF(ap + 3, v.w * w);
}

// In-place log_softmax over rows of 32; 32 lanes per row (2 rows per wave).
__global__ __launch_bounds__(256) void k_logsoftmax32(float* __restrict__ out,
                                                      const float* __restrict__ b,
                                                      int n_rows) {
    const long tid = (long)blockIdx.x * 256 + threadIdx.x;
    const int row = (int)(tid >> 5);
    const int c   = (int)(tid & 31);
    if (row >= n_rows) return;
    const float v = out[(long)row * 32 + c] + b[c];
    float m = v;
    #pragma unroll
    for (int off = 16; off; off >>= 1) m = fmaxf(m, __shfl_xor(m, off, 32));
    const float e = __expf(v - m);
    float s = e;
    #pragma unroll
    for (int off = 16; off; off >>= 1) s += __shfl_xor(s, off, 32);
    out[(long)row * 32 + c] = v - m - __logf(s);
}

extern "C" void kernel_launch(void* const* d_in, const int* in_sizes, int n_in,
                              void* d_out, int out_size, void* d_ws, size_t ws_size,
                              hipStream_t stream) {
    const float* x  = (const float*)d_in[0];
    const int*   ei = (const int*)  d_in[1];
    const float* W1 = (const float*)d_in[2];
    const float* b1 = (const float*)d_in[3];
    const float* W2 = (const float*)d_in[4];
    const float* b2 = (const float*)d_in[5];
    float* out = (float*)d_out;

    const int N = in_sizes[0] / 64;      // 100000
    const int E = in_sizes[1] / 2;       // 1600000
    const int* src = ei;
    const int* dst = ei + E;

    // workspace layout (floats)
    float* ws   = (float*)d_ws;
    const long nAl = ((long)N + 127) & ~127L;
    float* dinv = ws;                    // N      (deg -> dinv in place)
    float* h1   = ws + nAl;              // N*64
    float* agg1 = h1 + (long)N * 64;     // N*64
    float* h2   = h1;                    // reuse after scatter1 (N*32)
    // agg2 == d_out

    const int B = 256;
    auto cdiv = [](long a, long b) { return (int)((a + b - 1) / b); };

    k_init_deg<<<cdiv(N, B), B, 0, stream>>>(dinv, N);
    k_accum_deg<<<cdiv(E, B), B, 0, stream>>>(dst, dinv, E);
    k_mm<64, 64, false><<<2048, B, 0, stream>>>(x, W1, b1, h1, N);
    k_make_dinv<<<cdiv(N, B), B, 0, stream>>>(dinv, N);

    // layer 1 aggregate
    k_selfinit<64><<<cdiv((long)N * 16, B), B, 0, stream>>>(h1, dinv, agg1, (long)N * 16);
    k_scatter<64><<<cdiv((long)E * 16, B), B, 0, stream>>>(src, dst, dinv, h1, agg1, E);

    // layer 2 matmul (relu + b1 fused on input)
    k_mm<64, 32, true><<<2048, B, 0, stream>>>(agg1, W2, b1, h2, N);

    // layer 2 aggregate straight into d_out
    k_selfinit<32><<<cdiv((long)N * 8, B), B, 0, stream>>>(h2, dinv, out, (long)N * 8);
    k_scatter<32><<<cdiv((long)E * 8, B), B, 0, stream>>>(src, dst, dinv, h2, out, E);

    k_logsoftmax32<<<cdiv((long)N * 32, B), B, 0, stream>>>(out, b2, N);
}

// Round 3
// 488.453 us; speedup vs baseline: 4.5758x; 4.5758x over previous
//
#include <hip/hip_runtime.h>
#include <hip/hip_bf16.h>

// GCN 2-layer forward, fp32. CSR-by-dst built on device each launch; gather-side
// aggregation (no float atomics). Pipeline:
//   zero cnt -> hist(dst) -> scan(cnt)->offs,cursor,dinv -> fill slots(src)
//   h1 = x@W1 ; agg1 = self + gather ; h2 = relu(agg1+b1)@W2 ;
//   out = logsoftmax(self + gather + b2)

constexpr int SCAN_CHUNK = 1024;   // elements per 256-thread scan block

__global__ __launch_bounds__(256) void k_zero(int* __restrict__ p, int n) {
    int i = blockIdx.x * 256 + threadIdx.x;
    if (i < n) p[i] = 0;
}

__global__ __launch_bounds__(256) void k_hist(const int* __restrict__ dst,
                                              int* __restrict__ cnt, int E) {
    int e = blockIdx.x * 256 + threadIdx.x;
    if (e < E) atomicAdd(&cnt[dst[e]], 1);
}

// per-block sums of cnt chunks
__global__ __launch_bounds__(256) void k_scan1(const int* __restrict__ cnt,
                                               int* __restrict__ bsum, int N) {
    __shared__ int sm[256];
    const int t = threadIdx.x;
    const long base = (long)blockIdx.x * SCAN_CHUNK + t * 4;
    int s = 0;
    #pragma unroll
    for (int k = 0; k < 4; ++k) { long i = base + k; if (i < N) s += cnt[i]; }
    sm[t] = s; __syncthreads();
    for (int off = 128; off > 0; off >>= 1) {
        if (t < off) sm[t] += sm[t + off];
        __syncthreads();
    }
    if (t == 0) bsum[blockIdx.x] = sm[0];
}

// exclusive scan of block sums (nb <= 256)
__global__ __launch_bounds__(256) void k_scan2(const int* __restrict__ bsum,
                                               int* __restrict__ bofs, int nb) {
    __shared__ int sm[256];
    const int t = threadIdx.x;
    const int v = (t < nb) ? bsum[t] : 0;
    sm[t] = v; __syncthreads();
    for (int off = 1; off < 256; off <<= 1) {
        int u = (t >= off) ? sm[t - off] : 0;
        __syncthreads();
        sm[t] += u;
        __syncthreads();
    }
    if (t < nb) bofs[t] = sm[t] - v;   // exclusive
}

// final per-element exclusive scan + cursor copy + dinv = rsqrt(cnt+1)
__global__ __launch_bounds__(256) void k_scan3(const int* __restrict__ cnt,
                                               const int* __restrict__ bofs,
                                               int* __restrict__ offs,
                                               int* __restrict__ cursor,
                                               float* __restrict__ dinv, int N) {
    __shared__ int sm[256];
    const int t = threadIdx.x;
    const long base = (long)blockIdx.x * SCAN_CHUNK + t * 4;
    int c[4]; int s = 0;
    #pragma unroll
    for (int k = 0; k < 4; ++k) { long i = base + k; c[k] = (i < N) ? cnt[i] : 0; s += c[k]; }
    sm[t] = s; __syncthreads();
    for (int off = 1; off < 256; off <<= 1) {
        int u = (t >= off) ? sm[t - off] : 0;
        __syncthreads();
        sm[t] += u;
        __syncthreads();
    }
    int run = bofs[blockIdx.x] + (sm[t] - s);
    #pragma unroll
    for (int k = 0; k < 4; ++k) {
        long i = base + k;
        if (i < N) {
            offs[i] = run; cursor[i] = run;
            dinv[i] = rsqrtf((float)c[k] + 1.0f);
            run += c[k];
        }
    }
}

// slots[cursor[dst]++] = src  (int atomics only)
__global__ __launch_bounds__(256) void k_fill(const int* __restrict__ src,
                                              const int* __restrict__ dst,
                                              int* __restrict__ cursor,
                                              int* __restrict__ slots, int E) {
    int e = blockIdx.x * 256 + threadIdx.x;
    if (e >= E) return;
    int pos = atomicAdd(&cursor[dst[e]], 1);
    slots[pos] = src[e];
}

// out[r][c] = sum_k f(A[r][k]) * W[k][c];  f = relu(x + bin[k]) if TRANS_IN.
template<int IN_C, int OUT_C, bool TRANS_IN>
__global__ __launch_bounds__(256) void k_mm(const float* __restrict__ A,
                                            const float* __restrict__ W,
                                            const float* __restrict__ bin,
                                            float* __restrict__ out, int n_rows) {
    constexpr int C4   = OUT_C / 4;
    constexpr int ROWS = 256 / C4;
    __shared__ float Ws[IN_C][OUT_C];
    __shared__ float xs[ROWS][IN_C + 1];
    __shared__ float bs[IN_C];

    const int tid = threadIdx.x;
    for (int i = tid; i < IN_C * OUT_C; i += 256)
        Ws[i / OUT_C][i % OUT_C] = W[i];
    if (tid < IN_C) bs[tid] = TRANS_IN ? bin[tid] : 0.0f;

    const int c4 = (tid % C4) * 4;
    const int rl = tid / C4;
    const int tiles = (n_rows + ROWS - 1) / ROWS;

    for (int t = blockIdx.x; t < tiles; t += gridDim.x) {
        const int r0 = t * ROWS;
        __syncthreads();
        for (int i = tid; i < ROWS * IN_C; i += 256) {
            int r = i / IN_C, k = i % IN_C;
            float v = 0.0f;
            if (r0 + r < n_rows) {
                v = A[(long)(r0 + r) * IN_C + k];
                if (TRANS_IN) v = fmaxf(v + bs[k], 0.0f);
            }
            xs[r][k] = v;
        }
        __syncthreads();

        float4 acc = {0.f, 0.f, 0.f, 0.f};
        #pragma unroll
        for (int k = 0; k < IN_C; ++k) {
            const float a = xs[rl][k];
            const float4 w4 = *reinterpret_cast<const float4*>(&Ws[k][c4]);
            acc.x += a * w4.x; acc.y += a * w4.y;
            acc.z += a * w4.z; acc.w += a * w4.w;
        }
        const int row = r0 + rl;
        if (row < n_rows)
            *reinterpret_cast<float4*>(&out[(long)row * OUT_C + c4]) = acc;
    }
}

// One wave per node, lane = column (F=64). Gather-accumulate, single row store.
__global__ __launch_bounds__(256) void k_agg64(const int* __restrict__ offs,
                                               const int* __restrict__ cnt,
                                               const int* __restrict__ slots,
                                               const float* __restrict__ dinv,
                                               const float* __restrict__ h,
                                               float* __restrict__ agg, int N) {
    const int wid  = threadIdx.x >> 6;
    const int lane = threadIdx.x & 63;
    const int node = blockIdx.x * 4 + wid;
    if (node >= N) return;
    const int beg = offs[node], deg = cnt[node];
    const float dd = dinv[node];
    float acc = h[(long)node * 64 + lane] * dd * dd;   // self-loop term
    for (int j0 = 0; j0 < deg; j0 += 64) {
        const int m = min(64, deg - j0);
        int   sv = 0; float dv = 0.f;
        if (lane < m) { sv = slots[beg + j0 + lane]; dv = dinv[sv]; }
        for (int jj = 0; jj < m; ++jj) {
            const int   s = __shfl(sv, jj);
            const float w = __shfl(dv, jj) * dd;
            acc += w * h[(long)s * 64 + lane];
        }
    }
    agg[(long)node * 64 + lane] = acc;
}

// One wave per node, two edges per iteration (halves), F=32.
// Fuses self-loop + bias + log_softmax; writes d_out.
__global__ __launch_bounds__(256) void k_agg32_lsm(const int* __restrict__ offs,
                                                   const int* __restrict__ cnt,
                                                   const int* __restrict__ slots,
                                                   const float* __restrict__ dinv,
                                                   const float* __restrict__ h,
                                                   const float* __restrict__ b2,
                                                   float* __restrict__ out, int N) {
    const int wid  = threadIdx.x >> 6;
    const int lane = threadIdx.x & 63;
    const int half = lane >> 5;
    const int c    = lane & 31;
    const int node = blockIdx.x * 4 + wid;
    if (node >= N) return;
    const int beg = offs[node], deg = cnt[node];
    const float dd = dinv[node];
    float acc = 0.f;
    for (int j0 = 0; j0 < deg; j0 += 64) {
        const int m = min(64, deg - j0);
        int   sv = 0; float dv = 0.f;
        if (lane < m) { sv = slots[beg + j0 + lane]; dv = dinv[sv]; }
        for (int jj = 0; jj < m; jj += 2) {
            const int idx = jj + half;          // half 0: edge jj, half 1: edge jj+1
            const int   s = __shfl(sv, idx);
            const float w = __shfl(dv, idx) * dd;
            if (idx < m) acc += w * h[(long)s * 32 + c];
        }
    }
    acc += __shfl_xor(acc, 32);                 // combine halves; both halves now equal
    float v = acc + h[(long)node * 32 + c] * dd * dd + b2[c];
    float mx = v;
    #pragma unroll
    for (int off = 16; off; off >>= 1) mx = fmaxf(mx, __shfl_xor(mx, off));
    const float e = __expf(v - mx);
    float ssum = e;
    #pragma unroll
    for (int off = 16; off; off >>= 1) ssum += __shfl_xor(ssum, off);
    if (half == 0) out[(long)node * 32 + c] = v - mx - __logf(ssum);
}

extern "C" void kernel_launch(void* const* d_in, const int* in_sizes, int n_in,
                              void* d_out, int out_size, void* d_ws, size_t ws_size,
                              hipStream_t stream) {
    const float* x  = (const float*)d_in[0];
    const int*   ei = (const int*)  d_in[1];
    const float* W1 = (const float*)d_in[2];
    const float* b1 = (const float*)d_in[3];
    const float* W2 = (const float*)d_in[4];
    const float* b2 = (const float*)d_in[5];
    float* out = (float*)d_out;

    const int N = in_sizes[0] / 64;      // 100000
    const int E = in_sizes[1] / 2;       // 1600000
    const int* src = ei;
    const int* dst = ei + E;

    // workspace layout (256B-aligned blocks)
    auto align = [](long v) { return (v + 63) & ~63L; };   // in elements (4B) -> 256B
    char* wsb = (char*)d_ws;
    long o = 0;
    int*   cnt    = (int*)(wsb + o * 4); o = align(o + N);
    int*   offs   = (int*)(wsb + o * 4); o = align(o + N);
    int*   cursor = (int*)(wsb + o * 4); o = align(o + N);
    int*   bsum   = (int*)(wsb + o * 4); o = align(o + 256);
    int*   bofs   = (int*)(wsb + o * 4); o = align(o + 256);
    float* dinv   = (float*)(wsb + o * 4); o = align(o + N);
    int*   slots  = (int*)(wsb + o * 4); o = align(o + E);
    float* h1     = (float*)(wsb + o * 4); o = align(o + (long)N * 64);
    float* agg1   = (float*)(wsb + o * 4); o = align(o + (long)N * 64);
    float* h2     = h1;   // reuse after agg1 consumes h1

    const int B = 256;
    auto cdiv = [](long a, long b) { return (int)((a + b - 1) / b); };
    const int nb = cdiv(N, SCAN_CHUNK);   // 98 <= 256

    // CSR build + dinv
    k_zero <<<cdiv(N, B), B, 0, stream>>>(cnt, N);
    k_hist <<<cdiv(E, B), B, 0, stream>>>(dst, cnt, E);
    k_scan1<<<nb, B, 0, stream>>>(cnt, bsum, N);
    k_scan2<<<1,  B, 0, stream>>>(bsum, bofs, nb);
    k_scan3<<<nb, B, 0, stream>>>(cnt, bofs, offs, cursor, dinv, N);
    k_fill <<<cdiv(E, B), B, 0, stream>>>(src, dst, cursor, slots, E);

    // layer 1
    k_mm<64, 64, false><<<2048, B, 0, stream>>>(x, W1, b1, h1, N);
    k_agg64<<<cdiv(N, 4), B, 0, stream>>>(offs, cnt, slots, dinv, h1, agg1, N);

    // layer 2
    k_mm<64, 32, true><<<2048, B, 0, stream>>>(agg1, W2, b1, h2, N);
    k_agg32_lsm<<<cdiv(N, 4), B, 0, stream>>>(offs, cnt, slots, dinv, h2, b2, out, N);
}

// Round 6
// 367.143 us; speedup vs baseline: 6.0877x; 1.3304x over previous
//
#include <hip/hip_runtime.h>
#include <hip/hip_bf16.h>

// GCN 2-layer forward, fp32. CSR-by-dst built on device each launch; gather-side
// aggregation. Round 4: rank-fused histogram (atomic-free fill), nontemporal
// scatter store, grouped-float4 agg kernels.

constexpr int SCAN_CHUNK = 1024;

__global__ __launch_bounds__(256) void k_zero(int* __restrict__ p, int n) {
    int i = blockIdx.x * 256 + threadIdx.x;
    if (i < n) p[i] = 0;
}

// cnt[dst]++ and remember each edge's arrival rank (its slot within the node).
__global__ __launch_bounds__(256) void k_hist_rank(const int* __restrict__ dst,
                                                   int* __restrict__ cnt,
                                                   int* __restrict__ rank, int E) {
    int e = blockIdx.x * 256 + threadIdx.x;
    if (e < E) rank[e] = atomicAdd(&cnt[dst[e]], 1);
}

// per-block sums of cnt chunks
__global__ __launch_bounds__(256) void k_scan1(const int* __restrict__ cnt,
                                               int* __restrict__ bsum, int N) {
    __shared__ int sm[256];
    const int t = threadIdx.x;
    const long base = (long)blockIdx.x * SCAN_CHUNK + t * 4;
    int s = 0;
    #pragma unroll
    for (int k = 0; k < 4; ++k) { long i = base + k; if (i < N) s += cnt[i]; }
    sm[t] = s; __syncthreads();
    for (int off = 128; off > 0; off >>= 1) {
        if (t < off) sm[t] += sm[t + off];
        __syncthreads();
    }
    if (t == 0) bsum[blockIdx.x] = sm[0];
}

// exclusive scan of block sums (nb <= 256)
__global__ __launch_bounds__(256) void k_scan2(const int* __restrict__ bsum,
                                               int* __restrict__ bofs, int nb) {
    __shared__ int sm[256];
    const int t = threadIdx.x;
    const int v = (t < nb) ? bsum[t] : 0;
    sm[t] = v; __syncthreads();
    for (int off = 1; off < 256; off <<= 1) {
        int u = (t >= off) ? sm[t - off] : 0;
        __syncthreads();
        sm[t] += u;
        __syncthreads();
    }
    if (t < nb) bofs[t] = sm[t] - v;   // exclusive
}

// final per-element exclusive scan + dinv = rsqrt(cnt+1)
__global__ __launch_bounds__(256) void k_scan3(const int* __restrict__ cnt,
                                               const int* __restrict__ bofs,
                                               int* __restrict__ offs,
                                               float* __restrict__ dinv, int N) {
    __shared__ int sm[256];
    const int t = threadIdx.x;
    const long base = (long)blockIdx.x * SCAN_CHUNK + t * 4;
    int c[4]; int s = 0;
    #pragma unroll
    for (int k = 0; k < 4; ++k) { long i = base + k; c[k] = (i < N) ? cnt[i] : 0; s += c[k]; }
    sm[t] = s; __syncthreads();
    for (int off = 1; off < 256; off <<= 1) {
        int u = (t >= off) ? sm[t - off] : 0;
        __syncthreads();
        sm[t] += u;
        __syncthreads();
    }
    int run = bofs[blockIdx.x] + (sm[t] - s);
    #pragma unroll
    for (int k = 0; k < 4; ++k) {
        long i = base + k;
        if (i < N) {
            offs[i] = run;
            dinv[i] = rsqrtf((float)c[k] + 1.0f);
            run += c[k];
        }
    }
}

// slots[offs[dst] + rank] = src  — atomic-free, nontemporal scatter store.
__global__ __launch_bounds__(256) void k_fill(const int* __restrict__ src,
                                              const int* __restrict__ dst,
                                              const int* __restrict__ rank,
                                              const int* __restrict__ offs,
                                              int* __restrict__ slots, int E) {
    int e = blockIdx.x * 256 + threadIdx.x;
    if (e >= E) return;
    const int pos = offs[dst[e]] + rank[e];
    __builtin_nontemporal_store(src[e], &slots[pos]);
}

// out[r][c] = sum_k f(A[r][k]) * W[k][c];  f = relu(x + bin[k]) if TRANS_IN.
template<int IN_C, int OUT_C, bool TRANS_IN>
__global__ __launch_bounds__(256) void k_mm(const float* __restrict__ A,
                                            const float* __restrict__ W,
                                            const float* __restrict__ bin,
                                            float* __restrict__ out, int n_rows) {
    constexpr int C4   = OUT_C / 4;
    constexpr int ROWS = 256 / C4;
    __shared__ float Ws[IN_C][OUT_C];
    __shared__ float xs[ROWS][IN_C + 1];
    __shared__ float bs[IN_C];

    const int tid = threadIdx.x;
    for (int i = tid; i < IN_C * OUT_C; i += 256)
        Ws[i / OUT_C][i % OUT_C] = W[i];
    if (tid < IN_C) bs[tid] = TRANS_IN ? bin[tid] : 0.0f;

    const int c4 = (tid % C4) * 4;
    const int rl = tid / C4;
    const int tiles = (n_rows + ROWS - 1) / ROWS;

    for (int t = blockIdx.x; t < tiles; t += gridDim.x) {
        const int r0 = t * ROWS;
        __syncthreads();
        for (int i = tid; i < ROWS * IN_C; i += 256) {
            int r = i / IN_C, k = i % IN_C;
            float v = 0.0f;
            if (r0 + r < n_rows) {
                v = A[(long)(r0 + r) * IN_C + k];
                if (TRANS_IN) v = fmaxf(v + bs[k], 0.0f);
            }
            xs[r][k] = v;
        }
        __syncthreads();

        float4 acc = {0.f, 0.f, 0.f, 0.f};
        #pragma unroll
        for (int k = 0; k < IN_C; ++k) {
            const float a = xs[rl][k];
            const float4 w4 = *reinterpret_cast<const float4*>(&Ws[k][c4]);
            acc.x += a * w4.x; acc.y += a * w4.y;
            acc.z += a * w4.z; acc.w += a * w4.w;
        }
        const int row = r0 + rl;
        if (row < n_rows)
            *reinterpret_cast<float4*>(&out[(long)row * OUT_C + c4]) = acc;
    }
}

// One wave per node, F=64: 4 groups x 16 lanes; 4 edges/iter, float4 gathers.
__global__ __launch_bounds__(256) void k_agg64(const int* __restrict__ offs,
                                               const int* __restrict__ cnt,
                                               const int* __restrict__ slots,
                                               const float* __restrict__ dinv,
                                               const float* __restrict__ h,
                                               float* __restrict__ agg, int N) {
    const int wid  = threadIdx.x >> 6;
    const int lane = threadIdx.x & 63;
    const int grp  = lane >> 4;
    const int c4   = (lane & 15) * 4;
    const int node = blockIdx.x * 4 + wid;
    if (node >= N) return;
    const int beg = offs[node], deg = cnt[node];
    const float dd = dinv[node];
    float4 acc = {0.f, 0.f, 0.f, 0.f};
    for (int j0 = 0; j0 < deg; j0 += 64) {
        const int m = min(64, deg - j0);
        int sv = 0; float dv = 0.f;
        if (lane < m) { sv = slots[beg + j0 + lane]; dv = dinv[sv]; }
        for (int jj = 0; jj < m; jj += 4) {
            const int idx = jj + grp;
            const int   s = __shfl(sv, idx);
            const float w = __shfl(dv, idx) * dd;
            if (idx < m) {
                const float4 hv = *reinterpret_cast<const float4*>(&h[(long)s * 64 + c4]);
                acc.x += w * hv.x; acc.y += w * hv.y;
                acc.z += w * hv.z; acc.w += w * hv.w;
            }
        }
    }
    // combine the 4 edge-groups (lanes with equal lane&15 share columns)
    #pragma unroll
    for (int off = 16; off <= 32; off <<= 1) {
        acc.x += __shfl_xor(acc.x, off); acc.y += __shfl_xor(acc.y, off);
        acc.z += __shfl_xor(acc.z, off); acc.w += __shfl_xor(acc.w, off);
    }
    if (lane < 16) {
        const float4 hv = *reinterpret_cast<const float4*>(&h[(long)node * 64 + c4]);
        const float w = dd * dd;
        acc.x += w * hv.x; acc.y += w * hv.y;
        acc.z += w * hv.z; acc.w += w * hv.w;
        *reinterpret_cast<float4*>(&agg[(long)node * 64 + c4]) = acc;
    }
}

// One wave per node, F=32: 8 groups x 8 lanes; 8 edges/iter, float4 gathers.
// Fuses self-loop + bias + log_softmax; writes d_out.
__global__ __launch_bounds__(256) void k_agg32_lsm(const int* __restrict__ offs,
                                                   const int* __restrict__ cnt,
                                                   const int* __restrict__ slots,
                                                   const float* __restrict__ dinv,
                                                   const float* __restrict__ h,
                                                   const float* __restrict__ b2,
                                                   float* __restrict__ out, int N) {
    const int wid  = threadIdx.x >> 6;
    const int lane = threadIdx.x & 63;
    const int grp  = lane >> 3;
    const int c4   = (lane & 7) * 4;
    const int node = blockIdx.x * 4 + wid;
    if (node >= N) return;
    const int beg = offs[node], deg = cnt[node];
    const float dd = dinv[node];
    float4 acc = {0.f, 0.f, 0.f, 0.f};
    for (int j0 = 0; j0 < deg; j0 += 64) {
        const int m = min(64, deg - j0);
        int sv = 0; float dv = 0.f;
        if (lane < m) { sv = slots[beg + j0 + lane]; dv = dinv[sv]; }
        for (int jj = 0; jj < m; jj += 8) {
            const int idx = jj + grp;
            const int   s = __shfl(sv, idx);
            const float w = __shfl(dv, idx) * dd;
            if (idx < m) {
                const float4 hv = *reinterpret_cast<const float4*>(&h[(long)s * 32 + c4]);
                acc.x += w * hv.x; acc.y += w * hv.y;
                acc.z += w * hv.z; acc.w += w * hv.w;
            }
        }
    }
    // combine the 8 edge-groups (lanes with equal lane&7 share columns)
    #pragma unroll
    for (int off = 8; off <= 32; off <<= 1) {
        acc.x += __shfl_xor(acc.x, off); acc.y += __shfl_xor(acc.y, off);
        acc.z += __shfl_xor(acc.z, off); acc.w += __shfl_xor(acc.w, off);
    }
    // self-loop + bias (all lanes redundantly; octets replicate values)
    const float4 hv = *reinterpret_cast<const float4*>(&h[(long)node * 32 + c4]);
    const float4 bv = *reinterpret_cast<const float4*>(&b2[c4]);
    const float w = dd * dd;
    float4 v;
    v.x = acc.x + w * hv.x + bv.x; v.y = acc.y + w * hv.y + bv.y;
    v.z = acc.z + w * hv.z + bv.z; v.w = acc.w + w * hv.w + bv.w;
    // log_softmax across the 32 columns held by 8 lanes x float4
    float mx = fmaxf(fmaxf(v.x, v.y), fmaxf(v.z, v.w));
    #pragma unroll
    for (int off = 1; off < 8; off <<= 1) mx = fmaxf(mx, __shfl_xor(mx, off));
    float4 ev;
    ev.x = __expf(v.x - mx); ev.y = __expf(v.y - mx);
    ev.z = __expf(v.z - mx); ev.w = __expf(v.w - mx);
    float ss = ev.x + ev.y + ev.z + ev.w;
    #pragma unroll
    for (int off = 1; off < 8; off <<= 1) ss += __shfl_xor(ss, off);
    const float lg = mx + __logf(ss);
    if (lane < 8) {
        float4 o;
        o.x = v.x - lg; o.y = v.y - lg; o.z = v.z - lg; o.w = v.w - lg;
        *reinterpret_cast<float4*>(&out[(long)node * 32 + c4]) = o;
    }
}

extern "C" void kernel_launch(void* const* d_in, const int* in_sizes, int n_in,
                              void* d_out, int out_size, void* d_ws, size_t ws_size,
                              hipStream_t stream) {
    const float* x  = (const float*)d_in[0];
    const int*   ei = (const int*)  d_in[1];
    const float* W1 = (const float*)d_in[2];
    const float* b1 = (const float*)d_in[3];
    const float* W2 = (const float*)d_in[4];
    const float* b2 = (const float*)d_in[5];
    float* out = (float*)d_out;

    const int N = in_sizes[0] / 64;      // 100000
    const int E = in_sizes[1] / 2;       // 1600000
    const int* src = ei;
    const int* dst = ei + E;

    // workspace layout (256B-aligned blocks)
    auto align = [](long v) { return (v + 63) & ~63L; };
    char* wsb = (char*)d_ws;
    long o = 0;
    int*   cnt    = (int*)(wsb + o * 4); o = align(o + N);
    int*   offs   = (int*)(wsb + o * 4); o = align(o + N);
    int*   bsum   = (int*)(wsb + o * 4); o = align(o + 256);
    int*   bofs   = (int*)(wsb + o * 4); o = align(o + 256);
    float* dinv   = (float*)(wsb + o * 4); o = align(o + N);
    int*   slots  = (int*)(wsb + o * 4); o = align(o + E);
    float* h1     = (float*)(wsb + o * 4); o = align(o + (long)N * 64);
    float* agg1   = (float*)(wsb + o * 4); o = align(o + (long)N * 64);
    float* h2     = h1;                  // reuse after agg1 consumes h1
    int*   rank   = (int*)h1;            // overlay: rank dies before k_mm writes h1

    const int B = 256;
    auto cdiv = [](long a, long b) { return (int)((a + b - 1) / b); };
    const int nb = cdiv(N, SCAN_CHUNK);   // 98 <= 256

    // CSR build + dinv
    k_zero     <<<cdiv(N, B), B, 0, stream>>>(cnt, N);
    k_hist_rank<<<cdiv(E, B), B, 0, stream>>>(dst, cnt, rank, E);
    k_scan1    <<<nb, B, 0, stream>>>(cnt, bsum, N);
    k_scan2    <<<1,  B, 0, stream>>>(bsum, bofs, nb);
    k_scan3    <<<nb, B, 0, stream>>>(cnt, bofs, offs, dinv, N);
    k_fill     <<<cdiv(E, B), B, 0, stream>>>(src, dst, rank, offs, slots, E);

    // layer 1
    k_mm<64, 64, false><<<2048, B, 0, stream>>>(x, W1, b1, h1, N);
    k_agg64<<<cdiv(N, 4), B, 0, stream>>>(offs, cnt, slots, dinv, h1, agg1, N);

    // layer 2
    k_mm<64, 32, true><<<2048, B, 0, stream>>>(agg1, W2, b1, h2, N);
    k_agg32_lsm<<<cdiv(N, 4), B, 0, stream>>>(offs, cnt, slots, dinv, h2, b2, out, N);
}

// Round 8
// 353.816 us; speedup vs baseline: 6.3170x; 1.0377x over previous
//
#include <hip/hip_runtime.h>
#include <hip/hip_bf16.h>

// GCN 2-layer forward. CSR-by-dst built on device; gather-side aggregation.
// Round 7: h1/h2 stored as bf16 (exact widening on read, RN on write) to halve
// the dominant edge-gather traffic; unrolled gather loops for MLP.

constexpr int SCAN_CHUNK = 1024;

__device__ __forceinline__ unsigned short f2bf(float f) {   // round-to-nearest-even
    unsigned u = __float_as_uint(f);
    return (unsigned short)((u + 0x7FFF + ((u >> 16) & 1)) >> 16);
}
__device__ __forceinline__ float bf2f(unsigned short b) {   // exact widening
    return __uint_as_float((unsigned)b << 16);
}

__global__ __launch_bounds__(256) void k_zero(int* __restrict__ p, int n) {
    int i = blockIdx.x * 256 + threadIdx.x;
    if (i < n) p[i] = 0;
}

// cnt[dst]++ and remember each edge's arrival rank.
__global__ __launch_bounds__(256) void k_hist_rank(const int* __restrict__ dst,
                                                   int* __restrict__ cnt,
                                                   int* __restrict__ rank, int E) {
    int e = blockIdx.x * 256 + threadIdx.x;
    if (e < E) rank[e] = atomicAdd(&cnt[dst[e]], 1);
}

__global__ __launch_bounds__(256) void k_scan1(const int* __restrict__ cnt,
                                               int* __restrict__ bsum, int N) {
    __shared__ int sm[256];
    const int t = threadIdx.x;
    const long base = (long)blockIdx.x * SCAN_CHUNK + t * 4;
    int s = 0;
    #pragma unroll
    for (int k = 0; k < 4; ++k) { long i = base + k; if (i < N) s += cnt[i]; }
    sm[t] = s; __syncthreads();
    for (int off = 128; off > 0; off >>= 1) {
        if (t < off) sm[t] += sm[t + off];
        __syncthreads();
    }
    if (t == 0) bsum[blockIdx.x] = sm[0];
}

__global__ __launch_bounds__(256) void k_scan2(const int* __restrict__ bsum,
                                               int* __restrict__ bofs, int nb) {
    __shared__ int sm[256];
    const int t = threadIdx.x;
    const int v = (t < nb) ? bsum[t] : 0;
    sm[t] = v; __syncthreads();
    for (int off = 1; off < 256; off <<= 1) {
        int u = (t >= off) ? sm[t - off] : 0;
        __syncthreads();
        sm[t] += u;
        __syncthreads();
    }
    if (t < nb) bofs[t] = sm[t] - v;
}

__global__ __launch_bounds__(256) void k_scan3(const int* __restrict__ cnt,
                                               const int* __restrict__ bofs,
                                               int* __restrict__ offs,
                                               float* __restrict__ dinv, int N) {
    __shared__ int sm[256];
    const int t = threadIdx.x;
    const long base = (long)blockIdx.x * SCAN_CHUNK + t * 4;
    int c[4]; int s = 0;
    #pragma unroll
    for (int k = 0; k < 4; ++k) { long i = base + k; c[k] = (i < N) ? cnt[i] : 0; s += c[k]; }
    sm[t] = s; __syncthreads();
    for (int off = 1; off < 256; off <<= 1) {
        int u = (t >= off) ? sm[t - off] : 0;
        __syncthreads();
        sm[t] += u;
        __syncthreads();
    }
    int run = bofs[blockIdx.x] + (sm[t] - s);
    #pragma unroll
    for (int k = 0; k < 4; ++k) {
        long i = base + k;
        if (i < N) {
            offs[i] = run;
            dinv[i] = rsqrtf((float)c[k] + 1.0f);
            run += c[k];
        }
    }
}

// slots[offs[dst] + rank] = src  — atomic-free, nontemporal scatter store.
__global__ __launch_bounds__(256) void k_fill(const int* __restrict__ src,
                                              const int* __restrict__ dst,
                                              const int* __restrict__ rank,
                                              const int* __restrict__ offs,
                                              int* __restrict__ slots, int E) {
    int e = blockIdx.x * 256 + threadIdx.x;
    if (e >= E) return;
    const int pos = offs[dst[e]] + rank[e];
    __builtin_nontemporal_store(src[e], &slots[pos]);
}

// out[r][c] = sum_k f(A[r][k]) * W[k][c];  f = relu(x + bin[k]) if TRANS_IN.
// A is fp32; out is bf16.
template<int IN_C, int OUT_C, bool TRANS_IN>
__global__ __launch_bounds__(256) void k_mm(const float* __restrict__ A,
                                            const float* __restrict__ W,
                                            const float* __restrict__ bin,
                                            unsigned short* __restrict__ out,
                                            int n_rows) {
    constexpr int C4   = OUT_C / 4;
    constexpr int ROWS = 256 / C4;
    __shared__ float Ws[IN_C][OUT_C];
    __shared__ float xs[ROWS][IN_C + 1];
    __shared__ float bs[IN_C];

    const int tid = threadIdx.x;
    for (int i = tid; i < IN_C * OUT_C; i += 256)
        Ws[i / OUT_C][i % OUT_C] = W[i];
    if (tid < IN_C) bs[tid] = TRANS_IN ? bin[tid] : 0.0f;

    const int c4 = (tid % C4) * 4;
    const int rl = tid / C4;
    const int tiles = (n_rows + ROWS - 1) / ROWS;

    for (int t = blockIdx.x; t < tiles; t += gridDim.x) {
        const int r0 = t * ROWS;
        __syncthreads();
        for (int i = tid; i < ROWS * IN_C; i += 256) {
            int r = i / IN_C, k = i % IN_C;
            float v = 0.0f;
            if (r0 + r < n_rows) {
                v = A[(long)(r0 + r) * IN_C + k];
                if (TRANS_IN) v = fmaxf(v + bs[k], 0.0f);
            }
            xs[r][k] = v;
        }
        __syncthreads();

        float4 acc = {0.f, 0.f, 0.f, 0.f};
        #pragma unroll
        for (int k = 0; k < IN_C; ++k) {
            const float a = xs[rl][k];
            const float4 w4 = *reinterpret_cast<const float4*>(&Ws[k][c4]);
            acc.x += a * w4.x; acc.y += a * w4.y;
            acc.z += a * w4.z; acc.w += a * w4.w;
        }
        const int row = r0 + rl;
        if (row < n_rows) {
            ushort4 o;
            o.x = f2bf(acc.x); o.y = f2bf(acc.y);
            o.z = f2bf(acc.z); o.w = f2bf(acc.w);
            *reinterpret_cast<ushort4*>(&out[(long)row * OUT_C + c4]) = o;
        }
    }
}

// One wave per node, F=64: 4 groups x 16 lanes; 4 edges/iter, bf16x4 gathers.
__global__ __launch_bounds__(256) void k_agg64(const int* __restrict__ offs,
                                               const int* __restrict__ cnt,
                                               const int* __restrict__ slots,
                                               const float* __restrict__ dinv,
                                               const unsigned short* __restrict__ h,
                                               float* __restrict__ agg, int N) {
    const int wid  = threadIdx.x >> 6;
    const int lane = threadIdx.x & 63;
    const int grp  = lane >> 4;
    const int c4   = (lane & 15) * 4;
    const int node = blockIdx.x * 4 + wid;
    if (node >= N) return;
    const int beg = offs[node], deg = cnt[node];
    const float dd = dinv[node];
    float4 acc = {0.f, 0.f, 0.f, 0.f};
    for (int j0 = 0; j0 < deg; j0 += 64) {
        const int m = min(64, deg - j0);
        int sv = 0; float dv = 0.f;
        if (lane < m) { sv = slots[beg + j0 + lane]; dv = dinv[sv]; }
        #pragma unroll 4
        for (int jj = 0; jj < m; jj += 4) {
            const int idx = jj + grp;
            const int   s = __shfl(sv, idx);
            const float w = __shfl(dv, idx) * dd;
            if (idx < m) {
                const ushort4 hv = *reinterpret_cast<const ushort4*>(&h[(long)s * 64 + c4]);
                acc.x += w * bf2f(hv.x); acc.y += w * bf2f(hv.y);
                acc.z += w * bf2f(hv.z); acc.w += w * bf2f(hv.w);
            }
        }
    }
    #pragma unroll
    for (int off = 16; off <= 32; off <<= 1) {
        acc.x += __shfl_xor(acc.x, off); acc.y += __shfl_xor(acc.y, off);
        acc.z += __shfl_xor(acc.z, off); acc.w += __shfl_xor(acc.w, off);
    }
    if (lane < 16) {
        const ushort4 hv = *reinterpret_cast<const ushort4*>(&h[(long)node * 64 + c4]);
        const float w = dd * dd;
        acc.x += w * bf2f(hv.x); acc.y += w * bf2f(hv.y);
        acc.z += w * bf2f(hv.z); acc.w += w * bf2f(hv.w);
        *reinterpret_cast<float4*>(&agg[(long)node * 64 + c4]) = acc;
    }
}

// One wave per node, F=32: 8 groups x 8 lanes; 8 edges/iter, bf16x4 gathers.
// Fuses self-loop + bias + log_softmax; writes d_out (fp32).
__global__ __launch_bounds__(256) void k_agg32_lsm(const int* __restrict__ offs,
                                                   const int* __restrict__ cnt,
                                                   const int* __restrict__ slots,
                                                   const float* __restrict__ dinv,
                                                   const unsigned short* __restrict__ h,
                                                   const float* __restrict__ b2,
                                                   float* __restrict__ out, int N) {
    const int wid  = threadIdx.x >> 6;
    const int lane = threadIdx.x & 63;
    const int grp  = lane >> 3;
    const int c4   = (lane & 7) * 4;
    const int node = blockIdx.x * 4 + wid;
    if (node >= N) return;
    const int beg = offs[node], deg = cnt[node];
    const float dd = dinv[node];
    float4 acc = {0.f, 0.f, 0.f, 0.f};
    for (int j0 = 0; j0 < deg; j0 += 64) {
        const int m = min(64, deg - j0);
        int sv = 0; float dv = 0.f;
        if (lane < m) { sv = slots[beg + j0 + lane]; dv = dinv[sv]; }
        #pragma unroll 2
        for (int jj = 0; jj < m; jj += 8) {
            const int idx = jj + grp;
            const int   s = __shfl(sv, idx);
            const float w = __shfl(dv, idx) * dd;
            if (idx < m) {
                const ushort4 hv = *reinterpret_cast<const ushort4*>(&h[(long)s * 32 + c4]);
                acc.x += w * bf2f(hv.x); acc.y += w * bf2f(hv.y);
                acc.z += w * bf2f(hv.z); acc.w += w * bf2f(hv.w);
            }
        }
    }
    #pragma unroll
    for (int off = 8; off <= 32; off <<= 1) {
        acc.x += __shfl_xor(acc.x, off); acc.y += __shfl_xor(acc.y, off);
        acc.z += __shfl_xor(acc.z, off); acc.w += __shfl_xor(acc.w, off);
    }
    // self-loop + bias (all lanes redundantly; octets replicate values)
    const ushort4 hv = *reinterpret_cast<const ushort4*>(&h[(long)node * 32 + c4]);
    const float4 bv = *reinterpret_cast<const float4*>(&b2[c4]);
    const float w = dd * dd;
    float4 v;
    v.x = acc.x + w * bf2f(hv.x) + bv.x; v.y = acc.y + w * bf2f(hv.y) + bv.y;
    v.z = acc.z + w * bf2f(hv.z) + bv.z; v.w = acc.w + w * bf2f(hv.w) + bv.w;
    float mx = fmaxf(fmaxf(v.x, v.y), fmaxf(v.z, v.w));
    #pragma unroll
    for (int off = 1; off < 8; off <<= 1) mx = fmaxf(mx, __shfl_xor(mx, off));
    float4 ev;
    ev.x = __expf(v.x - mx); ev.y = __expf(v.y - mx);
    ev.z = __expf(v.z - mx); ev.w = __expf(v.w - mx);
    float ss = ev.x + ev.y + ev.z + ev.w;
    #pragma unroll
    for (int off = 1; off < 8; off <<= 1) ss += __shfl_xor(ss, off);
    const float lg = mx + __logf(ss);
    if (lane < 8) {
        float4 o;
        o.x = v.x - lg; o.y = v.y - lg; o.z = v.z - lg; o.w = v.w - lg;
        *reinterpret_cast<float4*>(&out[(long)node * 32 + c4]) = o;
    }
}

extern "C" void kernel_launch(void* const* d_in, const int* in_sizes, int n_in,
                              void* d_out, int out_size, void* d_ws, size_t ws_size,
                              hipStream_t stream) {
    const float* x  = (const float*)d_in[0];
    const int*   ei = (const int*)  d_in[1];
    const float* W1 = (const float*)d_in[2];
    const float* b1 = (const float*)d_in[3];
    const float* W2 = (const float*)d_in[4];
    const float* b2 = (const float*)d_in[5];
    float* out = (float*)d_out;

    const int N = in_sizes[0] / 64;      // 100000
    const int E = in_sizes[1] / 2;       // 1600000
    const int* src = ei;
    const int* dst = ei + E;

    // workspace layout (element offsets in 4B units, 256B-aligned blocks)
    auto align = [](long v) { return (v + 63) & ~63L; };
    char* wsb = (char*)d_ws;
    long o = 0;
    int*   cnt    = (int*)(wsb + o * 4); o = align(o + N);
    int*   offs   = (int*)(wsb + o * 4); o = align(o + N);
    int*   bsum   = (int*)(wsb + o * 4); o = align(o + 256);
    int*   bofs   = (int*)(wsb + o * 4); o = align(o + 256);
    float* dinv   = (float*)(wsb + o * 4); o = align(o + N);
    int*   slots  = (int*)(wsb + o * 4); o = align(o + E);
    unsigned short* h1 = (unsigned short*)(wsb + o * 4); o = align(o + (long)N * 32); // bf16 N*64
    float* agg1   = (float*)(wsb + o * 4); o = align(o + (long)N * 64);
    unsigned short* h2 = h1;             // bf16 N*32, reuse after agg64 consumes h1
    int*   rank   = (int*)h1;            // overlay: E ints (6.4MB) <= h1 region (12.8MB); dead before k_mm writes h1

    const int B = 256;
    auto cdiv = [](long a, long b) { return (int)((a + b - 1) / b); };
    const int nb = cdiv(N, SCAN_CHUNK);   // 98 <= 256

    // CSR build + dinv
    k_zero     <<<cdiv(N, B), B, 0, stream>>>(cnt, N);
    k_hist_rank<<<cdiv(E, B), B, 0, stream>>>(dst, cnt, rank, E);
    k_scan1    <<<nb, B, 0, stream>>>(cnt, bsum, N);
    k_scan2    <<<1,  B, 0, stream>>>(bsum, bofs, nb);
    k_scan3    <<<nb, B, 0, stream>>>(cnt, bofs, offs, dinv, N);
    k_fill     <<<cdiv(E, B), B, 0, stream>>>(src, dst, rank, offs, slots, E);

    // layer 1
    k_mm<64, 64, false><<<2048, B, 0, stream>>>(x, W1, b1, h1, N);
    k_agg64<<<cdiv(N, 4), B, 0, stream>>>(offs, cnt, slots, dinv, h1, agg1, N);

    // layer 2
    k_mm<64, 32, true><<<2048, B, 0, stream>>>(agg1, W2, b1, h2, N);
    k_agg32_lsm<<<cdiv(N, 4), B, 0, stream>>>(offs, cnt, slots, dinv, h2, b2, out, N);
}